// Round 11
// baseline (1172.073 us; speedup 1.0000x reference)
//
#include <hip/hip_runtime.h>
#include <hip/hip_bf16.h>

typedef unsigned int  u32;
typedef unsigned short u16;
typedef __attribute__((ext_vector_type(8))) short bf16x8;
typedef __attribute__((ext_vector_type(4))) float f32x4;
typedef __attribute__((ext_vector_type(2))) float f32x2;
typedef _Float16 f16;
typedef __attribute__((ext_vector_type(2))) _Float16 f16x2;

__device__ __forceinline__ float bfbits(u32 u){ union{u32 i; float f;} v; v.i=u; return v.f; }
__device__ __forceinline__ float bf2f(u16 u){ return bfbits(((u32)u)<<16); }
__device__ __forceinline__ u16 f2bf(float f){
  union{float f; u32 i;} v; v.f=f;
  u32 r = v.i + 0x7FFFu + ((v.i>>16)&1u);
  return (u16)(r>>16);
}
__device__ __forceinline__ u16 f2h_bits(float f){
  union{ f16 h; u16 u; } v; v.h=(f16)f; return v.u;
}
__device__ __forceinline__ f16x2 as_h2(u32 u){ union{u32 u; f16x2 h;} v; v.u=u; return v.h; }
__device__ __forceinline__ int clampi(int v, int lo, int hi){ return v<lo?lo:(v>hi?hi:v); }
__device__ __forceinline__ f32x2 unpack2(u32 q){
  f32x2 r; r.x = bfbits(q<<16); r.y = bfbits(q&0xFFFF0000u); return r;
}

#if defined(__has_builtin)
#if __has_builtin(__builtin_amdgcn_fdot2)
#define USE_FDOT2 1
#endif
#if __has_builtin(__builtin_amdgcn_update_dpp)
#define USE_DPP 1
#endif
#if __has_builtin(__builtin_amdgcn_global_load_lds)
#define USE_GLL 1
#endif
#endif

__device__ __forceinline__ float dot2acc(u32 a, u32 b, float c){
#ifdef USE_FDOT2
  return __builtin_amdgcn_fdot2(as_h2(a), as_h2(b), c, false);
#else
  f16x2 ha = as_h2(a), hb = as_h2(b);
  return c + (float)ha.x*(float)hb.x + (float)ha.y*(float)hb.y;
#endif
}

// sum over each 16-lane row via DPP rotate-adds (pure VALU; no LGKM chain).
__device__ __forceinline__ float row_reduce16(float x){
#ifdef USE_DPP
  union{float f; int i;} u, t;
  u.f = x; t.i = __builtin_amdgcn_update_dpp(0, u.i, 0x121, 0xF, 0xF, true); x += t.f; // row_ror:1
  u.f = x; t.i = __builtin_amdgcn_update_dpp(0, u.i, 0x122, 0xF, 0xF, true); x += t.f; // row_ror:2
  u.f = x; t.i = __builtin_amdgcn_update_dpp(0, u.i, 0x124, 0xF, 0xF, true); x += t.f; // row_ror:4
  u.f = x; t.i = __builtin_amdgcn_update_dpp(0, u.i, 0x128, 0xF, 0xF, true); x += t.f; // row_ror:8
  return x;
#else
  x += __shfl_xor(x,1); x += __shfl_xor(x,2);
  x += __shfl_xor(x,4); x += __shfl_xor(x,8);
  return x;
#endif
}

// ---------------- dtype detect: bf16 vs fp32 storage ----------------
__global__ void detect_kernel(const u16* __restrict__ xr, int* __restrict__ flag){
  __shared__ int cnt;
  if (threadIdx.x==0) cnt=0;
  __syncthreads();
  int c=0;
  for (int i=threadIdx.x; i<8192; i+=256){
    u16 u = xr[i];
    int e = (u>>7)&0xFF;
    if (e>=0x90 || u==0) c++;
  }
  atomicAdd(&cnt, c);
  __syncthreads();
  if (threadIdx.x==0) *flag = (cnt>16) ? 1 : 0;   // 1 = fp32, 0 = bf16
}

__device__ __forceinline__ float rdin(const void* p, int idx, int f){
  return f ? ((const float*)p)[idx] : bf2f(((const u16*)p)[idx]);
}

// ---------------- canonicalize big tensors (ONLY when fp32 input) ----------------
__global__ void canon_big(const void* __restrict__ xr, const void* __restrict__ ear,
                          const int* __restrict__ flag,
                          ushort4* __restrict__ xbf, ushort4* __restrict__ eabf,
                          int NX4, int NE4){
  int f = *flag;
  if (!f) return;                       // bf16: no canonicalization needed
  int i = blockIdx.x*blockDim.x + threadIdx.x;
  if (i < NX4){
    const float4 v = ((const float4*)xr)[i];
    ushort4 o; o.x=f2bf(v.x); o.y=f2bf(v.y); o.z=f2bf(v.z); o.w=f2bf(v.w);
    xbf[i]=o;
  } else if (i < NX4+NE4){
    int j = i - NX4;
    const float4 v = ((const float4*)ear)[j];
    ushort4 o; o.x=f2bf(v.x); o.y=f2bf(v.y); o.z=f2bf(v.z); o.w=f2bf(v.w);
    eabf[j]=o;
  }
}

// ---------------- canonicalize small tensors + zero deg ----------------
__global__ void canon_small(const int* __restrict__ flag,
   const void* Wl0, const void* Wr0, const void* Wl1, const void* Wr1,
   const void* We0, const void* We1,
   const void* bl0, const void* br0, const void* bias0, const void* att0,
   const void* bl1, const void* br1, const void* bias1, const void* att1,
   const void* fc1b, const void* fc2W, const void* fc2b, const void* fc1W,
   u16* __restrict__ wbf, u32* __restrict__ we0p, u32* __restrict__ we1p,
   float* __restrict__ params, int* __restrict__ deg, int N)
{
  int f = *flag;
  int i = blockIdx.x*blockDim.x + threadIdx.x;
  if (i < N) deg[i] = 0;
  if (i < 32768){
    { int c=i>>7, k=i&127;   // layer0: K=128, M=256 -> WT[c*128+k]
      wbf[i]        = f2bf(rdin(Wl0, k*256+c, f));
      wbf[32768+i]  = f2bf(rdin(Wr0, k*256+c, f)); }
    { int c=i>>8, k=i&255;   // layer1: K=256, M=128 -> WT[c*256+k]
      wbf[65536+i]  = f2bf(rdin(Wl1, k*128+c, f));
      wbf[98304+i]  = f2bf(rdin(Wr1, k*128+c, f)); }
  }
  if (i < 2048){ int c=i&255, p=i>>8;
    float lo = rdin(We0, (2*p)*256 + c, f);
    float hi = rdin(We0, (2*p+1)*256 + c, f);
    we0p[c*8+p] = (u32)f2h_bits(lo) | ((u32)f2h_bits(hi)<<16);
  }
  if (i < 1024){ int c=i&127, p=i>>7;
    float lo = rdin(We1, (2*p)*128 + c, f);
    float hi = rdin(We1, (2*p+1)*128 + c, f);
    we1p[c*8+p] = (u32)f2h_bits(lo) | ((u32)f2h_bits(hi)<<16);
  }
  if (i < 256){ params[i]=rdin(bl0,i,f); params[256+i]=rdin(br0,i,f);
                params[512+i]=rdin(bias0,i,f); params[768+i]=rdin(att0,i,f); }
  if (i < 128){ params[1024+i]=rdin(bl1,i,f); params[1152+i]=rdin(br1,i,f);
                params[1280+i]=rdin(bias1,i,f); params[1408+i]=rdin(att1,i,f);
                params[1536+i]=rdin(fc1b,i,f); params[1664+i]=rdin(fc2W,i,f); }
  if (i == 0) params[1792] = rdin(fc2b,0,f);
  if (i < 16384) params[1800+i] = rdin(fc1W,i,f);
}

// ---------------- CSR build ----------------
__global__ void hist_kernel(const int* __restrict__ ei, int* __restrict__ deg, int E, int N){
  int e = blockIdx.x*blockDim.x + threadIdx.x;
  if (e < E) atomicAdd(&deg[clampi(ei[E+e],0,N-1)], 1);
}

// Parallel 3-pass exclusive scan.
__global__ __launch_bounds__(1024) void scan1_kernel(const int* __restrict__ deg,
    int* __restrict__ incl, int* __restrict__ bsum, int n){
  __shared__ int lds[1024];
  int t = threadIdx.x;
  int i = blockIdx.x*1024 + t;
  int v = (i<n)? deg[i] : 0;
  lds[t]=v;
  __syncthreads();
  for (int off=1; off<1024; off<<=1){
    int add = (t>=off)? lds[t-off] : 0;
    __syncthreads();
    lds[t] += add;
    __syncthreads();
  }
  if (i<n) incl[i]=lds[t];
  if (t==1023) bsum[blockIdx.x]=lds[1023];
}
__global__ __launch_bounds__(1024) void scan2_kernel(int* __restrict__ bsum, int NB){
  __shared__ int lds[1024];
  int t = threadIdx.x;
  int v = (t<NB)? bsum[t] : 0;
  lds[t]=v;
  __syncthreads();
  for (int off=1; off<1024; off<<=1){
    int add = (t>=off)? lds[t-off] : 0;
    __syncthreads();
    lds[t] += add;
    __syncthreads();
  }
  if (t<NB) bsum[t] = lds[t]-v;   // exclusive
}
__global__ __launch_bounds__(1024) void scan3_kernel(const int* __restrict__ incl,
    const int* __restrict__ bsum, int* __restrict__ indptr, int* __restrict__ deg, int n){
  int i = blockIdx.x*1024 + threadIdx.x;
  if (i<n){
    int inc = incl[i], d = deg[i];
    int ex = bsum[blockIdx.x] + inc - d;
    indptr[i] = ex;
    deg[i] = 0;
    if (i==n-1) indptr[n] = ex + d;
  }
}

// scatter: write only eid (4B) per edge
__global__ void scatter_kernel(const int* __restrict__ ei, const int* __restrict__ indptr,
                               int* __restrict__ fill, int* __restrict__ eid, int E, int N){
  int e = blockIdx.x*blockDim.x + threadIdx.x;
  if (e < E){
    int d = clampi(ei[E+e], 0, N-1);
    int pos = clampi(indptr[d] + atomicAdd(&fill[d], 1), 0, E-1);
    eid[pos] = e;
  }
}

// pos-parallel payload gather; ea source selected by flag.
__global__ void csr_payload(const int* __restrict__ eid, const int* __restrict__ ei,
                            const u16* __restrict__ eabf, const void* __restrict__ ea_orig,
                            const int* __restrict__ flag,
                            int* __restrict__ csr_src, u32* __restrict__ ea_csr, int E, int N){
  const u16* src = (*flag) ? eabf : (const u16*)ea_orig;
  int pos = blockIdx.x*blockDim.x + threadIdx.x;
  if (pos < E){
    int e = clampi(eid[pos], 0, E-1);
    csr_src[pos] = clampi(ei[e], 0, N-1);
    const uint4* q = (const uint4*)(src + (size_t)e*16);
    uint4 a = q[0], b = q[1];
    u32 in[8] = {a.x,a.y,a.z,a.w,b.x,b.y,b.z,b.w};
    u32 o[8];
    #pragma unroll
    for (int k=0;k<8;k++){
      f32x2 p = unpack2(in[k]);
      o[k] = (u32)f2h_bits(p.x) | ((u32)f2h_bits(p.y)<<16);
    }
    uint4* op = (uint4*)(ea_csr + (size_t)pos*8);
    op[0] = make_uint4(o[0],o[1],o[2],o[3]);
    op[1] = make_uint4(o[4],o[5],o[6],o[7]);
  } else if (pos < E+64){
    csr_src[pos] = 0;
    uint4* op = (uint4*)(ea_csr + (size_t)pos*8);
    op[0] = make_uint4(0,0,0,0);
    op[1] = make_uint4(0,0,0,0);
  }
}

// ---------------- node transform GEMM (MFMA): XL = X@Wl+bl, XR = X@Wr+br ----------------
// single-pass X (r10): block owns MT m-tiles; af held in regs across all col-tiles.
template<int K, int M, int MT>
__global__ __launch_bounds__(256) void node_gemm(
    const u16* __restrict__ Xc, const void* __restrict__ xorig, const int* __restrict__ flag,
    const u16* __restrict__ WlT, const float* __restrict__ blf,
    const u16* __restrict__ WrT, const float* __restrict__ brf,
    u16* __restrict__ XL, u16* __restrict__ XR, int N)
{
  constexpr int KS = K/32;
  constexpr int NCT = 2*M/16;       // total col-tiles across XL|XR
  const u16* X = (flag && !*flag) ? (const u16*)xorig : Xc;
  int wave = threadIdx.x >> 6, lane = threadIdx.x & 63;
  int kq = (lane >> 4) * 8;
  int mbase = blockIdx.x*MT*16;

  bf16x8 af[MT][KS];
  #pragma unroll
  for (int r=0; r<MT; r++){
    int m = mbase + r*16 + (lane & 15);
    if (m >= N) m = N-1;
    const u16* xrow = X + (size_t)m*K;
    #pragma unroll
    for (int s=0; s<KS; s++) af[r][s] = *(const bf16x8*)(xrow + s*32 + kq);
  }

  for (int ct = wave; ct < NCT; ct += 4){
    int col = ct*16 + (lane & 15);
    bool isR = (col >= M);
    int c = isR ? col - M : col;
    const u16* WT = isR ? WrT : WlT;
    float bv = isR ? brf[c] : blf[c];
    u16* OUT = isR ? XR : XL;
    bf16x8 bfr[KS];
    const u16* wrow = WT + (size_t)c*K;
    #pragma unroll
    for (int s=0; s<KS; s++) bfr[s] = *(const bf16x8*)(wrow + s*32 + kq);
    #pragma unroll
    for (int r=0; r<MT; r++){
      f32x4 acc = {0.f,0.f,0.f,0.f};
      #pragma unroll
      for (int s=0; s<KS; s++)
        acc = __builtin_amdgcn_mfma_f32_16x16x32_bf16(af[r][s], bfr[s], acc, 0,0,0);
      #pragma unroll
      for (int q=0; q<4; q++){
        int node = mbase + r*16 + (lane>>4)*4 + q;
        if (node < N) OUT[(size_t)node*M + c] = f2bf(acc[q] + bv);
      }
    }
  }
}

// ---------------- fused score + softmax + aggregate ----------------
// r11: xl gather staged via ASYNC global_load_lds into wave-private double-buffered
// LDS (no barriers -> no vmcnt(0) drain; DMA stays in flight across the previous
// chunk's ~1300cy of math). One size=16 call gathers 2 full edge rows (M=256,
// lanes 0-31 edge j / 32-63 edge j+1) or 4 rows (M=128, 16 lanes each).
// src lane-selection uses explicit cndmask selects (compile-time array indices).
// ea/src loads stay register-resident (linear, cache-friendly).
template<int M, int CH>
__global__ __launch_bounds__(256) void fused_score_agg(
    const int* __restrict__ indptr, const int* __restrict__ csr_src,
    const u32* __restrict__ eaP,
    const u32* __restrict__ weP, const u16* __restrict__ xl,
    const u16* __restrict__ xr, const float* __restrict__ attf,
    const float* __restrict__ biasf, u16* __restrict__ outp, int N, int E)
{
  constexpr int VPT = M/64;       // 4 (M=256) or 2 (M=128)
  constexpr int VP2 = VPT/2;
  constexpr int C = M/4;
  int wvi = threadIdx.x>>6;
  int lane = threadIdx.x & 63;
  int c0 = lane*VPT;
  int h = lane>>4;

#ifdef USE_GLL
  __shared__ u16 sxl[4][2][CH*M];   // [wave][dbuf half][CH edge rows]
#endif

  u32 wp[8][VPT];
  #pragma unroll
  for (int c=0;c<VPT;c++){
    uint4 q0 = *(const uint4*)(weP + (u32)(c0+c)*8);
    uint4 q1 = *(const uint4*)(weP + (u32)(c0+c)*8 + 4);
    wp[0][c]=q0.x; wp[1][c]=q0.y; wp[2][c]=q0.z; wp[3][c]=q0.w;
    wp[4][c]=q1.x; wp[5][c]=q1.y; wp[6][c]=q1.z; wp[7][c]=q1.w;
  }
  float atv[VPT], bvv[VPT];
  #pragma unroll
  for (int c=0;c<VPT;c++){ atv[c] = attf[h*C + ((c0&(C-1)) + c)]; bvv[c] = biasf[c0+c]; }

  int nquads = (N+3)>>2;
  for (int nb = blockIdx.x; nb < nquads; nb += gridDim.x){
  int n = nb*4 + wvi;
  if (n < N){

  float xrv[VPT];
  if constexpr (VPT==4){
    uint2 q = *(const uint2*)(xr + (u32)n*M + c0);
    f32x2 a = unpack2(q.x), b = unpack2(q.y);
    xrv[0]=a.x; xrv[1]=a.y; xrv[2]=b.x; xrv[3]=b.y;
  } else {
    u32 q = *(const u32*)(xr + (u32)n*M + c0);
    f32x2 a = unpack2(q);
    xrv[0]=a.x; xrv[1]=a.y;
  }

  int s0 = clampi(indptr[n],0,E), s1 = clampi(indptr[n+1],s0,E);

  float m = -1e30f, d = 0.f;
  f32x2 acc2[VP2];
  #pragma unroll
  for (int q=0;q<VP2;q++) acc2[q] = (f32x2){0.f,0.f};

  struct Buf {
    int   src[CH];
    uint4 ea0[CH], ea1[CH];   // 16 f16 (8 u32) per edge
#ifndef USE_GLL
    uint2 x4[CH];             // VPT==4 gather (register fallback)
    u32   x2[CH];             // VPT==2 gather
#endif
  };
  Buf A, B;

  auto loadSrc = [&](Buf& Bf, int base){
    #pragma unroll
    for (int j=0;j<CH;j++) Bf.src[j] = csr_src[base+j];   // padded, no clamp
  };
  auto loadEA = [&](Buf& Bf, int base){
    #pragma unroll
    for (int j=0;j<CH;j++){
      const uint4* qp = (const uint4*)(eaP + (u32)(base+j)*8);
      Bf.ea0[j]=qp[0]; Bf.ea1[j]=qp[1];
    }
  };
  // stage xl rows for this buffer's chunk into its LDS half (async DMA),
  // or register-gather fallback.
  auto stage = [&](Buf& Bf, int half){
#ifdef USE_GLL
    u16* lbase = &sxl[wvi][half][0];
    if constexpr (VPT==4){
      // 2 edges per call: lanes 0-31 edge e2*2, lanes 32-63 edge e2*2+1; 16B/lane
      #pragma unroll
      for (int e2=0; e2<CH/2; e2++){
        int sj = (lane&32) ? Bf.src[e2*2+1] : Bf.src[e2*2];
        u32 off = (u32)sj*M + (lane&31)*8;        // u16 units; 16B per lane
        __builtin_amdgcn_global_load_lds(
          (const __attribute__((address_space(1))) void*)(xl + off),
          (__attribute__((address_space(3))) void*)(lbase + e2*2*M),
          16, 0, 0);
      }
    } else {
      // 4 edges in one call: 16 lanes per edge; 16B/lane covers the 256B row
      int lo = (lane&16) ? Bf.src[1] : Bf.src[0];
      int hi = (lane&16) ? Bf.src[3] : Bf.src[2];
      int sj = (lane&32) ? hi : lo;
      u32 off = (u32)sj*M + (lane&15)*8;
      __builtin_amdgcn_global_load_lds(
        (const __attribute__((address_space(1))) void*)(xl + off),
        (__attribute__((address_space(3))) void*)lbase,
        16, 0, 0);
    }
#else
    (void)half;
    #pragma unroll
    for (int j=0;j<CH;j++){
      u32 off = (u32)Bf.src[j]*M + c0;
      if constexpr (VPT==4) Bf.x4[j] = *(const uint2*)(xl + off);
      else                  Bf.x2[j] = *(const u32*)(xl + off);
    }
#endif
  };
  auto computeC = [&](Buf& Bf, int base, int half){
    (void)half;
    int cnt = s1-base; if (cnt>CH) cnt=CH;
    f32x2 xlv2[CH][VP2];
    float pj[CH];
    #pragma unroll
    for (int j=0;j<CH;j++){
#ifdef USE_GLL
      const u16* lb = &sxl[wvi][half][0];
      if constexpr (VPT==4){
        uint2 q = *(const uint2*)(lb + j*M + c0);   // ds_read_b64, 2-way = free
        xlv2[j][0] = unpack2(q.x); xlv2[j][1] = unpack2(q.y);
      } else {
        u32 q = *(const u32*)(lb + j*M + c0);       // ds_read_b32
        xlv2[j][0] = unpack2(q);
      }
#else
      if constexpr (VPT==4){
        xlv2[j][0] = unpack2(Bf.x4[j].x); xlv2[j][1] = unpack2(Bf.x4[j].y);
      } else {
        xlv2[j][0] = unpack2(Bf.x2[j]);
      }
#endif
      float s[VPT];
      #pragma unroll
      for (int c=0;c<VPT;c++){
        float xlc = (c&1) ? xlv2[j][c>>1].y : xlv2[j][c>>1].x;
        s[c] = xlc + xrv[c];
      }
      #pragma unroll
      for (int c=0;c<VPT;c++){
        s[c] = dot2acc(Bf.ea0[j].x, wp[0][c], s[c]);
        s[c] = dot2acc(Bf.ea0[j].y, wp[1][c], s[c]);
        s[c] = dot2acc(Bf.ea0[j].z, wp[2][c], s[c]);
        s[c] = dot2acc(Bf.ea0[j].w, wp[3][c], s[c]);
        s[c] = dot2acc(Bf.ea1[j].x, wp[4][c], s[c]);
        s[c] = dot2acc(Bf.ea1[j].y, wp[5][c], s[c]);
        s[c] = dot2acc(Bf.ea1[j].z, wp[6][c], s[c]);
        s[c] = dot2acc(Bf.ea1[j].w, wp[7][c], s[c]);
      }
      float pp = 0.f;
      #pragma unroll
      for (int c=0;c<VPT;c++){
        float v = s[c];
        float lv = fmaxf(v, 0.2f*v);
        pp = fmaf(lv, atv[c], pp);
      }
      pp = row_reduce16(pp);
      pj[j] = (j<cnt)? pp : -1e30f;
    }
    float mn = m;
    #pragma unroll
    for (int j=0;j<CH;j++) mn = fmaxf(mn, pj[j]);
    float sc = __expf(m - mn);
    float wvv[CH];
    #pragma unroll
    for (int j=0;j<CH;j++) wvv[j] = __expf(pj[j]-mn);
    float dd = d*sc;
    #pragma unroll
    for (int j=0;j<CH;j++) dd += wvv[j];
    d = dd;
    f32x2 scv = {sc,sc};
    #pragma unroll
    for (int q=0;q<VP2;q++){
      f32x2 a = acc2[q]*scv;
      #pragma unroll
      for (int j=0;j<CH;j++){
        f32x2 wj = {wvv[j], wvv[j]};
        a = __builtin_elementwise_fma(wj, xlv2[j][q], a);
      }
      acc2[q] = a;
    }
    m = mn;
  };

  int nch = (s1 - s0 + CH - 1)/CH;
  if (nch > 0){
    loadSrc(A, s0);
    stage(A, 0);
    loadEA(A, s0);
    if (nch > 1) loadSrc(B, s0+CH);
    int ci = 0;
    while (true){
      int baseA = s0 + ci*CH;
      if (ci+1 < nch){ stage(B, 1); loadEA(B, baseA+CH); }
      if (ci+2 < nch)  loadSrc(A, baseA+2*CH);
      computeC(A, baseA, 0);
      ci++;
      if (ci >= nch) break;
      int baseB = s0 + ci*CH;
      if (ci+1 < nch){ stage(A, 0); loadEA(A, baseB+CH); }
      if (ci+2 < nch)  loadSrc(B, baseB+2*CH);
      computeC(B, baseB, 1);
      ci++;
      if (ci >= nch) break;
    }
  }
  float rd = 1.f/(d + 1e-16f);
  f32x2 rdv = {rd, rd};
  u16* op = outp + (u32)n*M + c0;
  #pragma unroll
  for (int q=0;q<VP2;q++){
    f32x2 bb; bb.x = bvv[2*q]; bb.y = bvv[2*q+1];
    f32x2 o = __builtin_elementwise_fma(acc2[q], rdv, bb);
    o = __builtin_elementwise_max(o, (f32x2){0.f,0.f});
    u32 pk = ((u32)f2bf(o.y)<<16) | (u32)f2bf(o.x);
    *(u32*)(op + 2*q) = pk;
  }
  } // n < N
  } // grid-stride
}

// ---------------- mean pool + MLP head, one block per graph ----------------
__device__ __forceinline__ int lower_bound_dev(const int* a, int n, int key){
  int lo=0, hi=n;
  while (lo<hi){ int mid=(lo+hi)>>1; if (a[mid] < key) lo=mid+1; else hi=mid; }
  return lo;
}

__global__ __launch_bounds__(128) void pool_mlp_kernel(
    const u16* __restrict__ h2, const int* __restrict__ batch,
    const float* __restrict__ params, const int* __restrict__ flag,
    void* __restrict__ out, int N)
{
  int g = blockIdx.x, t = threadIdx.x;
  __shared__ int sh_lo, sh_hi;
  if (t==0) sh_lo = lower_bound_dev(batch, N, g);
  if (t==1) sh_hi = lower_bound_dev(batch, N, g+1);
  __syncthreads();
  int lo = clampi(sh_lo, 0, N), hi = clampi(sh_hi, lo, N);
  float s0=0.f,s1=0.f,s2=0.f,s3=0.f,s4=0.f,s5=0.f,s6=0.f,s7=0.f;
  int n = lo;
  for (; n+8<=hi; n+=8){
    s0 += bf2f(h2[(size_t)(n+0)*128 + t]);
    s1 += bf2f(h2[(size_t)(n+1)*128 + t]);
    s2 += bf2f(h2[(size_t)(n+2)*128 + t]);
    s3 += bf2f(h2[(size_t)(n+3)*128 + t]);
    s4 += bf2f(h2[(size_t)(n+4)*128 + t]);
    s5 += bf2f(h2[(size_t)(n+5)*128 + t]);
    s6 += bf2f(h2[(size_t)(n+6)*128 + t]);
    s7 += bf2f(h2[(size_t)(n+7)*128 + t]);
  }
  for (; n<hi; n++) s0 += bf2f(h2[(size_t)n*128 + t]);
  float s = ((s0+s1)+(s2+s3)) + ((s4+s5)+(s6+s7));
  float cnt = (float)(hi-lo);
  float pooled = s / fmaxf(cnt, 1.f);
  __shared__ float pl[128];
  pl[t] = pooled;
  __syncthreads();
  const float* fc1W = params + 1800;
  float z = 0.f;
  for (int k=0; k<128; k++) z += pl[k]*fc1W[k*128 + t];
  z += params[1536 + t];
  z = (z>0.f)? z : 0.f;
  __shared__ float red[128];
  red[t] = z * params[1664 + t];
  __syncthreads();
  for (int st=64; st>0; st>>=1){
    if (t<st) red[t] += red[t+st];
    __syncthreads();
  }
  if (t==0){
    float zz = red[0] + params[1792];
    float r = 1.f/(1.f + __expf(-zz));
    if (*flag) ((float*)out)[g] = r;
    else       ((u16*)out)[g] = f2bf(r);
  }
}

// ---------------- launch ----------------
extern "C" void kernel_launch(void* const* d_in, const int* in_sizes, int n_in,
                              void* d_out, int out_size, void* d_ws, size_t ws_size,
                              hipStream_t stream)
{
  const void* x     = d_in[0];
  const void* eattr = d_in[1];
  const int*  ei    = (const int*)d_in[2];
  const int*  batch = (const int*)d_in[3];

  int N = in_sizes[0] / 128;   // 50000
  int E = in_sizes[2] / 2;     // 800000
  int G = out_size;            // 64

  // Workspace layout (256 MB available):
  char* w = (char*)d_ws;
  int*   flag    = (int*)(w);                    // [0,4)
  int*   deg     = (int*)(w + 256);              // N ints
  int*   indptr  = (int*)(w + 200448);           // N+1
  int*   csr_src = (int*)(w + 400512);           // E+64 ints (padded)
  u32*   we0p    = (u32*)(w + 3601664);          // 2048 u32 (f16-pair packed)
  u32*   we1p    = (u32*)(w + 3610624);          // 1024 u32
  float* params  = (float*)(w + 3658240);        // 18184 f32
  u16*   wbf     = (u16*)(w + 3731200);          // 131072 bf16 (WT layouts)
  u16*   xbf     = (u16*)(w + 3993600);          // N*128
  u16*   eabf    = (u16*)(w + 16793600);         // E*16
  u16*   xl0     = (u16*)(w + 42393600);         // N*256 (layer1: N*128)
  u16*   xr0     = (u16*)(w + 67993600);         // N*256 (layer1: N*128)
  u16*   h1      = (u16*)(w + 93593600);         // N*256
  u16*   h2      = (u16*)(w + 119193600);        // N*128
  u32*   ea_csr  = (u32*)(w + 131993600);        // (E+64)*8 u32 (f16-pair packed, CSR order)
  int*   eid     = (int*)(w + 183193600);        // E ints (ends 186,393,600)
  int*   incl    = (int*)(w + 186400000);        // N ints (scan scratch)
  int*   bsum    = (int*)(w + 186700032);        // <=1024 ints

  detect_kernel<<<1, 256, 0, stream>>>((const u16*)x, flag);

  int NX4 = N*128/4, NE4 = E*16/4;
  canon_big<<<(NX4+NE4+255)/256, 256, 0, stream>>>(x, eattr, flag,
      (ushort4*)xbf, (ushort4*)eabf, NX4, NE4);
  canon_small<<<(N+255)/256, 256, 0, stream>>>(flag,
      d_in[4], d_in[6], d_in[11], d_in[13],
      d_in[8], d_in[15],
      d_in[5], d_in[7], d_in[10], d_in[9],
      d_in[12], d_in[14], d_in[17], d_in[16],
      d_in[19], d_in[20], d_in[21], d_in[18],
      wbf, we0p, we1p, params, deg, N);

  hist_kernel<<<(E+255)/256, 256, 0, stream>>>(ei, deg, E, N);
  int NB = (N + 1023)/1024;
  scan1_kernel<<<NB, 1024, 0, stream>>>(deg, incl, bsum, N);
  scan2_kernel<<<1, 1024, 0, stream>>>(bsum, NB);
  scan3_kernel<<<NB, 1024, 0, stream>>>(incl, bsum, indptr, deg, N);
  scatter_kernel<<<(E+255)/256, 256, 0, stream>>>(ei, indptr, deg, eid, E, N);
  csr_payload<<<(E+64+255)/256, 256, 0, stream>>>(eid, ei, eabf, eattr, flag,
      csr_src, ea_csr, E, N);

  int mt = (N+15)/16;
  int fgrid = 2048;
  // layer 0: MT=4 m-tiles, single-pass X, waves loop over 32 col-tiles
  node_gemm<128,256,4><<<(mt+3)/4, 256, 0, stream>>>(xbf, x, flag,
      wbf, params, wbf+32768, params+256, xl0, xr0, N);
  fused_score_agg<256,4><<<fgrid, 256, 0, stream>>>(indptr, csr_src, ea_csr,
      we0p, xl0, xr0, params+768, params+512, h1, N, E);

  // layer 1: MT=2 (K=256 doubles af cost), waves loop over 16 col-tiles
  node_gemm<256,128,2><<<(mt+1)/2, 256, 0, stream>>>(h1, nullptr, nullptr,
      wbf+65536, params+1024, wbf+98304, params+1152, xl0, xr0, N);
  fused_score_agg<128,4><<<fgrid, 256, 0, stream>>>(indptr, csr_src, ea_csr,
      we1p, xl0, xr0, params+1408, params+1280, h2, N, E);

  // pool + MLP + sigmoid
  pool_mlp_kernel<<<G, 128, 0, stream>>>(h2, batch, params, flag, d_out, N);
}

// Round 12
// 677.026 us; speedup vs baseline: 1.7312x; 1.7312x over previous
//
#include <hip/hip_runtime.h>
#include <hip/hip_bf16.h>

typedef unsigned int  u32;
typedef unsigned short u16;
typedef __attribute__((ext_vector_type(8))) short bf16x8;
typedef __attribute__((ext_vector_type(4))) float f32x4;
typedef __attribute__((ext_vector_type(2))) float f32x2;
typedef _Float16 f16;
typedef __attribute__((ext_vector_type(2))) _Float16 f16x2;

__device__ __forceinline__ float bfbits(u32 u){ union{u32 i; float f;} v; v.i=u; return v.f; }
__device__ __forceinline__ float bf2f(u16 u){ return bfbits(((u32)u)<<16); }
__device__ __forceinline__ u16 f2bf(float f){
  union{float f; u32 i;} v; v.f=f;
  u32 r = v.i + 0x7FFFu + ((v.i>>16)&1u);
  return (u16)(r>>16);
}
__device__ __forceinline__ u16 f2h_bits(float f){
  union{ f16 h; u16 u; } v; v.h=(f16)f; return v.u;
}
__device__ __forceinline__ f16x2 as_h2(u32 u){ union{u32 u; f16x2 h;} v; v.u=u; return v.h; }
__device__ __forceinline__ int clampi(int v, int lo, int hi){ return v<lo?lo:(v>hi?hi:v); }
__device__ __forceinline__ f32x2 unpack2(u32 q){
  f32x2 r; r.x = bfbits(q<<16); r.y = bfbits(q&0xFFFF0000u); return r;
}

#if defined(__has_builtin)
#if __has_builtin(__builtin_amdgcn_fdot2)
#define USE_FDOT2 1
#endif
#if __has_builtin(__builtin_amdgcn_update_dpp)
#define USE_DPP 1
#endif
#endif

__device__ __forceinline__ float dot2acc(u32 a, u32 b, float c){
#ifdef USE_FDOT2
  return __builtin_amdgcn_fdot2(as_h2(a), as_h2(b), c, false);
#else
  f16x2 ha = as_h2(a), hb = as_h2(b);
  return c + (float)ha.x*(float)hb.x + (float)ha.y*(float)hb.y;
#endif
}

// sum over each 16-lane row via DPP rotate-adds (pure VALU; no LGKM chain).
__device__ __forceinline__ float row_reduce16(float x){
#ifdef USE_DPP
  union{float f; int i;} u, t;
  u.f = x; t.i = __builtin_amdgcn_update_dpp(0, u.i, 0x121, 0xF, 0xF, true); x += t.f; // row_ror:1
  u.f = x; t.i = __builtin_amdgcn_update_dpp(0, u.i, 0x122, 0xF, 0xF, true); x += t.f; // row_ror:2
  u.f = x; t.i = __builtin_amdgcn_update_dpp(0, u.i, 0x124, 0xF, 0xF, true); x += t.f; // row_ror:4
  u.f = x; t.i = __builtin_amdgcn_update_dpp(0, u.i, 0x128, 0xF, 0xF, true); x += t.f; // row_ror:8
  return x;
#else
  x += __shfl_xor(x,1); x += __shfl_xor(x,2);
  x += __shfl_xor(x,4); x += __shfl_xor(x,8);
  return x;
#endif
}

// ---------------- dtype detect: bf16 vs fp32 storage ----------------
__global__ void detect_kernel(const u16* __restrict__ xr, int* __restrict__ flag){
  __shared__ int cnt;
  if (threadIdx.x==0) cnt=0;
  __syncthreads();
  int c=0;
  for (int i=threadIdx.x; i<8192; i+=256){
    u16 u = xr[i];
    int e = (u>>7)&0xFF;
    if (e>=0x90 || u==0) c++;
  }
  atomicAdd(&cnt, c);
  __syncthreads();
  if (threadIdx.x==0) *flag = (cnt>16) ? 1 : 0;   // 1 = fp32, 0 = bf16
}

__device__ __forceinline__ float rdin(const void* p, int idx, int f){
  return f ? ((const float*)p)[idx] : bf2f(((const u16*)p)[idx]);
}

// ---------------- canonicalize big tensors (ONLY when fp32 input) ----------------
__global__ void canon_big(const void* __restrict__ xr, const void* __restrict__ ear,
                          const int* __restrict__ flag,
                          ushort4* __restrict__ xbf, ushort4* __restrict__ eabf,
                          int NX4, int NE4){
  int f = *flag;
  if (!f) return;                       // bf16: no canonicalization needed
  int i = blockIdx.x*blockDim.x + threadIdx.x;
  if (i < NX4){
    const float4 v = ((const float4*)xr)[i];
    ushort4 o; o.x=f2bf(v.x); o.y=f2bf(v.y); o.z=f2bf(v.z); o.w=f2bf(v.w);
    xbf[i]=o;
  } else if (i < NX4+NE4){
    int j = i - NX4;
    const float4 v = ((const float4*)ear)[j];
    ushort4 o; o.x=f2bf(v.x); o.y=f2bf(v.y); o.z=f2bf(v.z); o.w=f2bf(v.w);
    eabf[j]=o;
  }
}

// ---------------- canonicalize small tensors + zero deg + zero pooled ----------------
__global__ void canon_small(const int* __restrict__ flag,
   const void* Wl0, const void* Wr0, const void* Wl1, const void* Wr1,
   const void* We0, const void* We1,
   const void* bl0, const void* br0, const void* bias0, const void* att0,
   const void* bl1, const void* br1, const void* bias1, const void* att1,
   const void* fc1b, const void* fc2W, const void* fc2b, const void* fc1W,
   u16* __restrict__ wbf, u32* __restrict__ we0p, u32* __restrict__ we1p,
   float* __restrict__ params, int* __restrict__ deg, float* __restrict__ pooled, int N)
{
  int f = *flag;
  int i = blockIdx.x*blockDim.x + threadIdx.x;
  if (i < N) deg[i] = 0;
  if (i < 8192) pooled[i] = 0.f;
  if (i < 32768){
    { int c=i>>7, k=i&127;   // layer0: K=128, M=256 -> WT[c*128+k]
      wbf[i]        = f2bf(rdin(Wl0, k*256+c, f));
      wbf[32768+i]  = f2bf(rdin(Wr0, k*256+c, f)); }
    { int c=i>>8, k=i&255;   // layer1: K=256, M=128 -> WT[c*256+k]
      wbf[65536+i]  = f2bf(rdin(Wl1, k*128+c, f));
      wbf[98304+i]  = f2bf(rdin(Wr1, k*128+c, f)); }
  }
  if (i < 2048){ int c=i&255, p=i>>8;
    float lo = rdin(We0, (2*p)*256 + c, f);
    float hi = rdin(We0, (2*p+1)*256 + c, f);
    we0p[c*8+p] = (u32)f2h_bits(lo) | ((u32)f2h_bits(hi)<<16);
  }
  if (i < 1024){ int c=i&127, p=i>>7;
    float lo = rdin(We1, (2*p)*128 + c, f);
    float hi = rdin(We1, (2*p+1)*128 + c, f);
    we1p[c*8+p] = (u32)f2h_bits(lo) | ((u32)f2h_bits(hi)<<16);
  }
  if (i < 256){ params[i]=rdin(bl0,i,f); params[256+i]=rdin(br0,i,f);
                params[512+i]=rdin(bias0,i,f); params[768+i]=rdin(att0,i,f); }
  if (i < 128){ params[1024+i]=rdin(bl1,i,f); params[1152+i]=rdin(br1,i,f);
                params[1280+i]=rdin(bias1,i,f); params[1408+i]=rdin(att1,i,f);
                params[1536+i]=rdin(fc1b,i,f); params[1664+i]=rdin(fc2W,i,f); }
  if (i == 0) params[1792] = rdin(fc2b,0,f);
  if (i < 16384) params[1800+i] = rdin(fc1W,i,f);
}

// ---------------- CSR build ----------------
__global__ void hist_kernel(const int* __restrict__ ei, int* __restrict__ deg, int E, int N){
  int e = blockIdx.x*blockDim.x + threadIdx.x;
  if (e < E) atomicAdd(&deg[clampi(ei[E+e],0,N-1)], 1);
}

// Parallel 3-pass exclusive scan.
__global__ __launch_bounds__(1024) void scan1_kernel(const int* __restrict__ deg,
    int* __restrict__ incl, int* __restrict__ bsum, int n){
  __shared__ int lds[1024];
  int t = threadIdx.x;
  int i = blockIdx.x*1024 + t;
  int v = (i<n)? deg[i] : 0;
  lds[t]=v;
  __syncthreads();
  for (int off=1; off<1024; off<<=1){
    int add = (t>=off)? lds[t-off] : 0;
    __syncthreads();
    lds[t] += add;
    __syncthreads();
  }
  if (i<n) incl[i]=lds[t];
  if (t==1023) bsum[blockIdx.x]=lds[1023];
}
__global__ __launch_bounds__(1024) void scan2_kernel(int* __restrict__ bsum, int NB){
  __shared__ int lds[1024];
  int t = threadIdx.x;
  int v = (t<NB)? bsum[t] : 0;
  lds[t]=v;
  __syncthreads();
  for (int off=1; off<1024; off<<=1){
    int add = (t>=off)? lds[t-off] : 0;
    __syncthreads();
    lds[t] += add;
    __syncthreads();
  }
  if (t<NB) bsum[t] = lds[t]-v;   // exclusive
}
__global__ __launch_bounds__(1024) void scan3_kernel(const int* __restrict__ incl,
    const int* __restrict__ bsum, int* __restrict__ indptr, int* __restrict__ deg, int n){
  int i = blockIdx.x*1024 + threadIdx.x;
  if (i<n){
    int inc = incl[i], d = deg[i];
    int ex = bsum[blockIdx.x] + inc - d;
    indptr[i] = ex;
    deg[i] = 0;
    if (i==n-1) indptr[n] = ex + d;
  }
}

// scatter: write only eid (4B) per edge
__global__ void scatter_kernel(const int* __restrict__ ei, const int* __restrict__ indptr,
                               int* __restrict__ fill, int* __restrict__ eid, int E, int N){
  int e = blockIdx.x*blockDim.x + threadIdx.x;
  if (e < E){
    int d = clampi(ei[E+e], 0, N-1);
    int pos = clampi(indptr[d] + atomicAdd(&fill[d], 1), 0, E-1);
    eid[pos] = e;
  }
}

// pos-parallel payload gather; ea source selected by flag.
__global__ void csr_payload(const int* __restrict__ eid, const int* __restrict__ ei,
                            const u16* __restrict__ eabf, const void* __restrict__ ea_orig,
                            const int* __restrict__ flag,
                            int* __restrict__ csr_src, u32* __restrict__ ea_csr, int E, int N){
  const u16* src = (*flag) ? eabf : (const u16*)ea_orig;
  int pos = blockIdx.x*blockDim.x + threadIdx.x;
  if (pos < E){
    int e = clampi(eid[pos], 0, E-1);
    csr_src[pos] = clampi(ei[e], 0, N-1);
    const uint4* q = (const uint4*)(src + (size_t)e*16);
    uint4 a = q[0], b = q[1];
    u32 in[8] = {a.x,a.y,a.z,a.w,b.x,b.y,b.z,b.w};
    u32 o[8];
    #pragma unroll
    for (int k=0;k<8;k++){
      f32x2 p = unpack2(in[k]);
      o[k] = (u32)f2h_bits(p.x) | ((u32)f2h_bits(p.y)<<16);
    }
    uint4* op = (uint4*)(ea_csr + (size_t)pos*8);
    op[0] = make_uint4(o[0],o[1],o[2],o[3]);
    op[1] = make_uint4(o[4],o[5],o[6],o[7]);
  } else if (pos < E+64){
    csr_src[pos] = 0;
    uint4* op = (uint4*)(ea_csr + (size_t)pos*8);
    op[0] = make_uint4(0,0,0,0);
    op[1] = make_uint4(0,0,0,0);
  }
}

// ---------------- node transform GEMM (MFMA): XL = X@Wl+bl, XR = X@Wr+br ----------------
// single-pass X (r10): block owns MT m-tiles; af held in regs across all col-tiles.
template<int K, int M, int MT>
__global__ __launch_bounds__(256) void node_gemm(
    const u16* __restrict__ Xc, const void* __restrict__ xorig, const int* __restrict__ flag,
    const u16* __restrict__ WlT, const float* __restrict__ blf,
    const u16* __restrict__ WrT, const float* __restrict__ brf,
    u16* __restrict__ XL, u16* __restrict__ XR, int N)
{
  constexpr int KS = K/32;
  constexpr int NCT = 2*M/16;       // total col-tiles across XL|XR
  const u16* X = (flag && !*flag) ? (const u16*)xorig : Xc;
  int wave = threadIdx.x >> 6, lane = threadIdx.x & 63;
  int kq = (lane >> 4) * 8;
  int mbase = blockIdx.x*MT*16;

  bf16x8 af[MT][KS];
  #pragma unroll
  for (int r=0; r<MT; r++){
    int m = mbase + r*16 + (lane & 15);
    if (m >= N) m = N-1;
    const u16* xrow = X + (size_t)m*K;
    #pragma unroll
    for (int s=0; s<KS; s++) af[r][s] = *(const bf16x8*)(xrow + s*32 + kq);
  }

  for (int ct = wave; ct < NCT; ct += 4){
    int col = ct*16 + (lane & 15);
    bool isR = (col >= M);
    int c = isR ? col - M : col;
    const u16* WT = isR ? WrT : WlT;
    float bv = isR ? brf[c] : blf[c];
    u16* OUT = isR ? XR : XL;
    bf16x8 bfr[KS];
    const u16* wrow = WT + (size_t)c*K;
    #pragma unroll
    for (int s=0; s<KS; s++) bfr[s] = *(const bf16x8*)(wrow + s*32 + kq);
    #pragma unroll
    for (int r=0; r<MT; r++){
      f32x4 acc = {0.f,0.f,0.f,0.f};
      #pragma unroll
      for (int s=0; s<KS; s++)
        acc = __builtin_amdgcn_mfma_f32_16x16x32_bf16(af[r][s], bfr[s], acc, 0,0,0);
      #pragma unroll
      for (int q=0; q<4; q++){
        int node = mbase + r*16 + (lane>>4)*4 + q;
        if (node < N) OUT[(size_t)node*M + c] = f2bf(acc[q] + bv);
      }
    }
  }
}

// ---------------- fused score + softmax + aggregate (EXACT r6/r10 version) ----------------
template<int M, int CH>
__global__ __launch_bounds__(256) void fused_score_agg(
    const int* __restrict__ indptr, const int* __restrict__ csr_src,
    const u32* __restrict__ eaP,
    const u32* __restrict__ weP, const u16* __restrict__ xl,
    const u16* __restrict__ xr, const float* __restrict__ attf,
    const float* __restrict__ biasf, u16* __restrict__ outp, int N, int E)
{
  constexpr int VPT = M/64;       // 4 (M=256) or 2 (M=128)
  constexpr int VP2 = VPT/2;
  constexpr int C = M/4;
  int wvi = threadIdx.x>>6;
  int lane = threadIdx.x & 63;
  int c0 = lane*VPT;
  int h = lane>>4;

  u32 wp[8][VPT];
  #pragma unroll
  for (int c=0;c<VPT;c++){
    uint4 q0 = *(const uint4*)(weP + (u32)(c0+c)*8);
    uint4 q1 = *(const uint4*)(weP + (u32)(c0+c)*8 + 4);
    wp[0][c]=q0.x; wp[1][c]=q0.y; wp[2][c]=q0.z; wp[3][c]=q0.w;
    wp[4][c]=q1.x; wp[5][c]=q1.y; wp[6][c]=q1.z; wp[7][c]=q1.w;
  }
  float atv[VPT], bvv[VPT];
  #pragma unroll
  for (int c=0;c<VPT;c++){ atv[c] = attf[h*C + ((c0&(C-1)) + c)]; bvv[c] = biasf[c0+c]; }

  int nquads = (N+3)>>2;
  for (int nb = blockIdx.x; nb < nquads; nb += gridDim.x){
  int n = nb*4 + wvi;
  if (n < N){

  float xrv[VPT];
  if constexpr (VPT==4){
    uint2 q = *(const uint2*)(xr + (u32)n*M + c0);
    f32x2 a = unpack2(q.x), b = unpack2(q.y);
    xrv[0]=a.x; xrv[1]=a.y; xrv[2]=b.x; xrv[3]=b.y;
  } else {
    u32 q = *(const u32*)(xr + (u32)n*M + c0);
    f32x2 a = unpack2(q);
    xrv[0]=a.x; xrv[1]=a.y;
  }

  int s0 = clampi(indptr[n],0,E), s1 = clampi(indptr[n+1],s0,E);

  float m = -1e30f, d = 0.f;
  f32x2 acc2[VP2];
  #pragma unroll
  for (int q=0;q<VP2;q++) acc2[q] = (f32x2){0.f,0.f};

  struct Buf {
    int   src[CH];
    uint4 ea0[CH], ea1[CH];   // 16 f16 (8 u32) per edge
    uint2 x4[CH];             // VPT==4 gather
    u32   x2[CH];             // VPT==2 gather
  };
  Buf A, B;

  auto loadSrc = [&](Buf& Bf, int base){
    #pragma unroll
    for (int j=0;j<CH;j++) Bf.src[j] = csr_src[base+j];   // padded, no clamp
  };
  auto loadEA = [&](Buf& Bf, int base){
    #pragma unroll
    for (int j=0;j<CH;j++){
      const uint4* qp = (const uint4*)(eaP + (u32)(base+j)*8);
      Bf.ea0[j]=qp[0]; Bf.ea1[j]=qp[1];
    }
  };
  auto gath = [&](Buf& Bf){
    #pragma unroll
    for (int j=0;j<CH;j++){
      u32 off = (u32)Bf.src[j]*M + c0;
      if constexpr (VPT==4) Bf.x4[j] = *(const uint2*)(xl + off);
      else                  Bf.x2[j] = *(const u32*)(xl + off);
    }
  };
  auto computeC = [&](Buf& Bf, int base){
    int cnt = s1-base; if (cnt>CH) cnt=CH;
    f32x2 xlv2[CH][VP2];
    float pj[CH];
    #pragma unroll
    for (int j=0;j<CH;j++){
      if constexpr (VPT==4){
        xlv2[j][0] = unpack2(Bf.x4[j].x); xlv2[j][1] = unpack2(Bf.x4[j].y);
      } else {
        xlv2[j][0] = unpack2(Bf.x2[j]);
      }
      float s[VPT];
      #pragma unroll
      for (int c=0;c<VPT;c++){
        float xlc = (c&1) ? xlv2[j][c>>1].y : xlv2[j][c>>1].x;
        s[c] = xlc + xrv[c];
      }
      #pragma unroll
      for (int c=0;c<VPT;c++){
        s[c] = dot2acc(Bf.ea0[j].x, wp[0][c], s[c]);
        s[c] = dot2acc(Bf.ea0[j].y, wp[1][c], s[c]);
        s[c] = dot2acc(Bf.ea0[j].z, wp[2][c], s[c]);
        s[c] = dot2acc(Bf.ea0[j].w, wp[3][c], s[c]);
        s[c] = dot2acc(Bf.ea1[j].x, wp[4][c], s[c]);
        s[c] = dot2acc(Bf.ea1[j].y, wp[5][c], s[c]);
        s[c] = dot2acc(Bf.ea1[j].z, wp[6][c], s[c]);
        s[c] = dot2acc(Bf.ea1[j].w, wp[7][c], s[c]);
      }
      float pp = 0.f;
      #pragma unroll
      for (int c=0;c<VPT;c++){
        float v = s[c];
        float lv = fmaxf(v, 0.2f*v);
        pp = fmaf(lv, atv[c], pp);
      }
      pp = row_reduce16(pp);
      pj[j] = (j<cnt)? pp : -1e30f;
    }
    float mn = m;
    #pragma unroll
    for (int j=0;j<CH;j++) mn = fmaxf(mn, pj[j]);
    float sc = __expf(m - mn);
    float wvv[CH];
    #pragma unroll
    for (int j=0;j<CH;j++) wvv[j] = __expf(pj[j]-mn);
    float dd = d*sc;
    #pragma unroll
    for (int j=0;j<CH;j++) dd += wvv[j];
    d = dd;
    f32x2 scv = {sc,sc};
    #pragma unroll
    for (int q=0;q<VP2;q++){
      f32x2 a = acc2[q]*scv;
      #pragma unroll
      for (int j=0;j<CH;j++){
        f32x2 wj = {wvv[j], wvv[j]};
        a = __builtin_elementwise_fma(wj, xlv2[j][q], a);
      }
      acc2[q] = a;
    }
    m = mn;
  };

  int nch = (s1 - s0 + CH - 1)/CH;
  if (nch > 0){
    loadSrc(A, s0);
    gath(A);
    loadEA(A, s0);
    if (nch > 1) loadSrc(B, s0+CH);
    int ci = 0;
    while (true){
      int baseA = s0 + ci*CH;
      if (ci+1 < nch){ gath(B); loadEA(B, baseA+CH); }
      if (ci+2 < nch)  loadSrc(A, baseA+2*CH);
      computeC(A, baseA);
      ci++;
      if (ci >= nch) break;
      int baseB = s0 + ci*CH;
      if (ci+1 < nch){ gath(A); loadEA(A, baseB+CH); }
      if (ci+2 < nch)  loadSrc(B, baseB+2*CH);
      computeC(B, baseB);
      ci++;
      if (ci >= nch) break;
    }
  }
  float rd = 1.f/(d + 1e-16f);
  f32x2 rdv = {rd, rd};
  u16* op = outp + (u32)n*M + c0;
  #pragma unroll
  for (int q=0;q<VP2;q++){
    f32x2 bb; bb.x = bvv[2*q]; bb.y = bvv[2*q+1];
    f32x2 o = __builtin_elementwise_fma(acc2[q], rdv, bb);
    o = __builtin_elementwise_max(o, (f32x2){0.f,0.f});
    u32 pk = ((u32)f2bf(o.y)<<16) | (u32)f2bf(o.x);
    *(u32*)(op + 2*q) = pk;
  }
  } // n < N
  } // grid-stride
}

// ---------------- pooling (8-way split per graph) + MLP head ----------------
__device__ __forceinline__ int lower_bound_dev(const int* a, int n, int key){
  int lo=0, hi=n;
  while (lo<hi){ int mid=(lo+hi)>>1; if (a[mid] < key) lo=mid+1; else hi=mid; }
  return lo;
}

// 512 blocks: graph g = bid>>3, part = bid&7. Partial column sums -> atomicAdd.
__global__ __launch_bounds__(128) void pool_partial(
    const u16* __restrict__ h2, const int* __restrict__ batch,
    float* __restrict__ pooled, int N)
{
  int g = blockIdx.x >> 3, part = blockIdx.x & 7, t = threadIdx.x;
  __shared__ int sh_lo, sh_hi;
  if (t==0) sh_lo = lower_bound_dev(batch, N, g);
  if (t==1) sh_hi = lower_bound_dev(batch, N, g+1);
  __syncthreads();
  int lo = clampi(sh_lo, 0, N), hi = clampi(sh_hi, lo, N);
  int len = hi - lo;
  int b0 = lo + (int)(((long long)len*part)>>3);
  int b1 = lo + (int)(((long long)len*(part+1))>>3);
  if (b1 <= b0) return;
  float s0=0.f,s1=0.f,s2=0.f,s3=0.f,s4=0.f,s5=0.f,s6=0.f,s7=0.f;
  int n = b0;
  for (; n+8<=b1; n+=8){
    s0 += bf2f(h2[(size_t)(n+0)*128 + t]);
    s1 += bf2f(h2[(size_t)(n+1)*128 + t]);
    s2 += bf2f(h2[(size_t)(n+2)*128 + t]);
    s3 += bf2f(h2[(size_t)(n+3)*128 + t]);
    s4 += bf2f(h2[(size_t)(n+4)*128 + t]);
    s5 += bf2f(h2[(size_t)(n+5)*128 + t]);
    s6 += bf2f(h2[(size_t)(n+6)*128 + t]);
    s7 += bf2f(h2[(size_t)(n+7)*128 + t]);
  }
  for (; n<b1; n++) s0 += bf2f(h2[(size_t)n*128 + t]);
  float s = ((s0+s1)+(s2+s3)) + ((s4+s5)+(s6+s7));
  atomicAdd(&pooled[g*128 + t], s);
}

__global__ __launch_bounds__(128) void mlp_kernel(
    const float* __restrict__ pooled, const int* __restrict__ batch,
    const float* __restrict__ params, const int* __restrict__ flag,
    void* __restrict__ out, int N)
{
  int g = blockIdx.x, t = threadIdx.x;
  __shared__ int sh_lo, sh_hi;
  if (t==0) sh_lo = lower_bound_dev(batch, N, g);
  if (t==1) sh_hi = lower_bound_dev(batch, N, g+1);
  __syncthreads();
  int lo = clampi(sh_lo, 0, N), hi = clampi(sh_hi, lo, N);
  float cnt = (float)(hi-lo);
  float pv = pooled[g*128 + t] / fmaxf(cnt, 1.f);
  __shared__ float pl[128];
  pl[t] = pv;
  __syncthreads();
  const float* fc1W = params + 1800;
  float z = 0.f;
  for (int k=0; k<128; k++) z += pl[k]*fc1W[k*128 + t];
  z += params[1536 + t];
  z = (z>0.f)? z : 0.f;
  __shared__ float red[128];
  red[t] = z * params[1664 + t];
  __syncthreads();
  for (int st=64; st>0; st>>=1){
    if (t<st) red[t] += red[t+st];
    __syncthreads();
  }
  if (t==0){
    float zz = red[0] + params[1792];
    float r = 1.f/(1.f + __expf(-zz));
    if (*flag) ((float*)out)[g] = r;
    else       ((u16*)out)[g] = f2bf(r);
  }
}

// ---------------- launch ----------------
extern "C" void kernel_launch(void* const* d_in, const int* in_sizes, int n_in,
                              void* d_out, int out_size, void* d_ws, size_t ws_size,
                              hipStream_t stream)
{
  const void* x     = d_in[0];
  const void* eattr = d_in[1];
  const int*  ei    = (const int*)d_in[2];
  const int*  batch = (const int*)d_in[3];

  int N = in_sizes[0] / 128;   // 50000
  int E = in_sizes[2] / 2;     // 800000
  int G = out_size;            // 64

  // Workspace layout (256 MB available):
  char* w = (char*)d_ws;
  int*   flag    = (int*)(w);                    // [0,4)
  int*   deg     = (int*)(w + 256);              // N ints
  int*   indptr  = (int*)(w + 200448);           // N+1
  int*   csr_src = (int*)(w + 400512);           // E+64 ints (padded)
  u32*   we0p    = (u32*)(w + 3601664);          // 2048 u32 (f16-pair packed)
  u32*   we1p    = (u32*)(w + 3610624);          // 1024 u32
  float* params  = (float*)(w + 3658240);        // 18184 f32
  u16*   wbf     = (u16*)(w + 3731200);          // 131072 bf16 (WT layouts)
  u16*   xbf     = (u16*)(w + 3993600);          // N*128
  u16*   eabf    = (u16*)(w + 16793600);         // E*16
  u16*   xl0     = (u16*)(w + 42393600);         // N*256 (layer1: N*128)
  u16*   xr0     = (u16*)(w + 67993600);         // N*256 (layer1: N*128)
  u16*   h1      = (u16*)(w + 93593600);         // N*256
  u16*   h2      = (u16*)(w + 119193600);        // N*128
  u32*   ea_csr  = (u32*)(w + 131993600);        // (E+64)*8 u32 (f16-pair packed, CSR order)
  int*   eid     = (int*)(w + 183193600);        // E ints (ends 186,393,600)
  int*   incl    = (int*)(w + 186400000);        // N ints (scan scratch)
  int*   bsum    = (int*)(w + 186700032);        // <=1024 ints
  float* pooled  = (float*)(w + 186710016);      // 64*128 f32 (32 KB)

  detect_kernel<<<1, 256, 0, stream>>>((const u16*)x, flag);

  int NX4 = N*128/4, NE4 = E*16/4;
  canon_big<<<(NX4+NE4+255)/256, 256, 0, stream>>>(x, eattr, flag,
      (ushort4*)xbf, (ushort4*)eabf, NX4, NE4);
  canon_small<<<(N+255)/256, 256, 0, stream>>>(flag,
      d_in[4], d_in[6], d_in[11], d_in[13],
      d_in[8], d_in[15],
      d_in[5], d_in[7], d_in[10], d_in[9],
      d_in[12], d_in[14], d_in[17], d_in[16],
      d_in[19], d_in[20], d_in[21], d_in[18],
      wbf, we0p, we1p, params, deg, pooled, N);

  hist_kernel<<<(E+255)/256, 256, 0, stream>>>(ei, deg, E, N);
  int NB = (N + 1023)/1024;
  scan1_kernel<<<NB, 1024, 0, stream>>>(deg, incl, bsum, N);
  scan2_kernel<<<1, 1024, 0, stream>>>(bsum, NB);
  scan3_kernel<<<NB, 1024, 0, stream>>>(incl, bsum, indptr, deg, N);
  scatter_kernel<<<(E+255)/256, 256, 0, stream>>>(ei, indptr, deg, eid, E, N);
  csr_payload<<<(E+64+255)/256, 256, 0, stream>>>(eid, ei, eabf, eattr, flag,
      csr_src, ea_csr, E, N);

  int mt = (N+15)/16;
  int fgrid = 2048;
  // layer 0: MT=4 m-tiles, single-pass X, waves loop over 32 col-tiles
  node_gemm<128,256,4><<<(mt+3)/4, 256, 0, stream>>>(xbf, x, flag,
      wbf, params, wbf+32768, params+256, xl0, xr0, N);
  fused_score_agg<256,4><<<fgrid, 256, 0, stream>>>(indptr, csr_src, ea_csr,
      we0p, xl0, xr0, params+768, params+512, h1, N, E);

  // layer 1: MT=2 (K=256 doubles af cost), waves loop over 16 col-tiles
  node_gemm<256,128,2><<<(mt+1)/2, 256, 0, stream>>>(h1, nullptr, nullptr,
      wbf+65536, params+1024, wbf+98304, params+1152, xl0, xr0, N);
  fused_score_agg<128,4><<<fgrid, 256, 0, stream>>>(indptr, csr_src, ea_csr,
      we1p, xl0, xr0, params+1408, params+1280, h2, N, E);

  // pool (8-way split) + MLP + sigmoid
  pool_partial<<<G*8, 128, 0, stream>>>(h2, batch, pooled, N);
  mlp_kernel<<<G, 128, 0, stream>>>(pooled, batch, params, flag, d_out, N);
}